// Round 15
// baseline (524.843 us; speedup 1.0000x reference)
//
#include <hip/hip_runtime.h>
#include <stdint.h>

using bf16_t = __bf16;
using bf16x8 = __attribute__((ext_vector_type(8))) bf16_t;
using bf16x4 = __attribute__((ext_vector_type(4))) bf16_t;
using f32x4  = __attribute__((ext_vector_type(4))) float;

#define MFMA16(a,b,c) __builtin_amdgcn_mfma_f32_16x16x32_bf16((a),(b),(c),0,0,0)

__device__ inline f32x4 zero4() { f32x4 z; z[0]=0.f; z[1]=0.f; z[2]=0.f; z[3]=0.f; return z; }

// ---------------------------------------------------------------------------
// Kernel 1: RMSNorm + QKV projection. VERBATIM from round 13/14 (PASSED).
// vt_ws stored PV-fragment-tiled: 16B unit = ((kt*2+ks2)*8+f8)*64 + lane.
// ---------------------------------------------------------------------------
__global__ __launch_bounds__(256) void qkv_kernel(
    const float* __restrict__ x, const float* __restrict__ nscale,
    const float* __restrict__ wq, const float* __restrict__ wk,
    const float* __restrict__ wv, const float* __restrict__ bv,
    bf16_t* __restrict__ q_ws, bf16_t* __restrict__ k_ws,
    bf16_t* __restrict__ vt_ws)
{
    __shared__ __align__(16) union SM {
        bf16_t h[64 * 136];                                     // 17408 B
        struct { bf16_t qk[64 * 264]; bf16_t vt[128 * 72]; } o; // 33792+18432 B
    } sm;

    const int tid   = threadIdx.x;
    const int mbase = blockIdx.x * 64;

    // ---- Phase 1: RMSNorm -> sm.h (bf16, row stride 136) ----
    {
        const int row = tid >> 2;
        const int qtr = tid & 3;
        const float4* xr = reinterpret_cast<const float4*>(x + (size_t)(mbase + row) * 128) + qtr * 8;
        const float4* sc = reinterpret_cast<const float4*>(nscale) + qtr * 8;
        float4 xv[8];
        float ss = 0.f;
#pragma unroll
        for (int i = 0; i < 8; ++i) {
            xv[i] = xr[i];
            ss += xv[i].x*xv[i].x + xv[i].y*xv[i].y + xv[i].z*xv[i].z + xv[i].w*xv[i].w;
        }
        ss += __shfl_xor(ss, 1);
        ss += __shfl_xor(ss, 2);
        const float rs = rsqrtf(ss * (1.0f / 128.0f) + 1e-6f);
#pragma unroll
        for (int i = 0; i < 8; ++i) {
            const float4 s = sc[i];
            bf16x4 hv;
            hv[0] = (bf16_t)(xv[i].x * rs * s.x);
            hv[1] = (bf16_t)(xv[i].y * rs * s.y);
            hv[2] = (bf16_t)(xv[i].z * rs * s.z);
            hv[3] = (bf16_t)(xv[i].w * rs * s.w);
            *reinterpret_cast<bf16x4*>(&sm.h[row * 136 + qtr * 32 + i * 4]) = hv;
        }
    }
    __syncthreads();

    const int lane = tid & 63;
    const int w    = tid >> 6;
    const int lrow = lane & 15;
    const int lgrp = lane >> 4;

    // ---- A fragments: full 64x128 h tile ----
    bf16x8 afr[4][4];
#pragma unroll
    for (int mt = 0; mt < 4; ++mt)
#pragma unroll
        for (int ks = 0; ks < 4; ++ks)
            afr[mt][ks] = *reinterpret_cast<const bf16x8*>(
                &sm.h[(mt * 16 + lrow) * 136 + ks * 32 + lgrp * 8]);
    __syncthreads();   // h dead; LDS reused as sm.o

    // ---- GEMM per nt tile; results -> LDS ----
#pragma unroll
    for (int nt = 0; nt < 6; ++nt) {
        const int gcol = w * 96 + nt * 16;                 // wave-uniform, 0..383
        const float* wptr = (gcol < 128) ? wq : ((gcol < 256) ? wk : wv);
        const bool is_v = (gcol >= 256);

        f32x4 acc[4];
#pragma unroll
        for (int mt = 0; mt < 4; ++mt) acc[mt] = zero4();

        const float* wrow = wptr + (size_t)((gcol & 127) + lrow) * 128 + lgrp * 8;
#pragma unroll
        for (int ks = 0; ks < 4; ++ks) {
            const float4 w0 = *reinterpret_cast<const float4*>(wrow + ks * 32);
            const float4 w1 = *reinterpret_cast<const float4*>(wrow + ks * 32 + 4);
            bf16x8 bfr;
            bfr[0] = (bf16_t)w0.x; bfr[1] = (bf16_t)w0.y;
            bfr[2] = (bf16_t)w0.z; bfr[3] = (bf16_t)w0.w;
            bfr[4] = (bf16_t)w1.x; bfr[5] = (bf16_t)w1.y;
            bfr[6] = (bf16_t)w1.z; bfr[7] = (bf16_t)w1.w;
            if (!is_v) {
#pragma unroll
                for (int mt = 0; mt < 4; ++mt)
                    acc[mt] = MFMA16(bfr, afr[mt][ks], acc[mt]);   // C[feat][pos]
            } else {
#pragma unroll
                for (int mt = 0; mt < 4; ++mt)
                    acc[mt] = MFMA16(afr[mt][ks], bfr, acc[mt]);   // C[pos][feat]
            }
        }

        if (!is_v) {
            // per-lane: pos = mt*16+lrow, feats gcol+lgrp*4 .. +3
#pragma unroll
            for (int mt = 0; mt < 4; ++mt) {
                bf16x4 o4;
                o4[0] = (bf16_t)acc[mt][0]; o4[1] = (bf16_t)acc[mt][1];
                o4[2] = (bf16_t)acc[mt][2]; o4[3] = (bf16_t)acc[mt][3];
                *reinterpret_cast<bf16x4*>(&sm.o.qk[(mt*16 + lrow) * 264 + gcol + lgrp*4]) = o4;
            }
        } else {
            // per-lane: feat = (gcol-256)+lrow, pos = mt*16+lgrp*4 .. +3
            const int f = (gcol - 256) + lrow;
            const float bvf = bv[f];
#pragma unroll
            for (int mt = 0; mt < 4; ++mt) {
                bf16x4 o4;
                o4[0] = (bf16_t)(acc[mt][0] + bvf); o4[1] = (bf16_t)(acc[mt][1] + bvf);
                o4[2] = (bf16_t)(acc[mt][2] + bvf); o4[3] = (bf16_t)(acc[mt][3] + bvf);
                *reinterpret_cast<bf16x4*>(&sm.o.vt[f * 72 + mt*16 + lgrp*4]) = o4;
            }
        }
    }
    __syncthreads();

    // ---- coalesced store-out ----
    const int p  = mbase >> 9;
    const int kb = mbase & 511;
#pragma unroll
    for (int it = 0; it < 8; ++it) {
        const int c   = it * 256 + tid;     // 2048 chunks of 8 bf16
        const int pos = c >> 5;
        const int col = (c & 31) * 8;
        const bf16x8 vv = *reinterpret_cast<const bf16x8*>(&sm.o.qk[pos * 264 + col]);
        bf16_t* dst = (col < 128) ? (q_ws + (size_t)(mbase + pos) * 128 + col)
                                  : (k_ws + (size_t)(mbase + pos) * 128 + (col - 128));
        *reinterpret_cast<bf16x8*>(dst) = vv;
    }
    // V: LDS vt[f][ko..ko+7] -> fragment-tiled global layout.
    {
        const int kt = kb >> 6;
#pragma unroll
        for (int it = 0; it < 4; ++it) {
            const int c  = it * 256 + tid;  // 1024 chunks of 8 bf16
            const int f  = c >> 3;
            const int ko = (c & 7) * 8;
            const int unit = ((kt * 2 + (ko >> 5)) * 8 + (f >> 4)) * 64
                             + ((ko >> 3) & 3) * 16 + (f & 15);
            *reinterpret_cast<bf16x8*>(vt_ws + (size_t)p * 65536 + (size_t)unit * 8) =
                *reinterpret_cast<const bf16x8*>(&sm.o.vt[f * 72 + ko]);
        }
    }
}

// ---------------------------------------------------------------------------
// Kernel 2: flash attention. R14 structure (K+V single-buffered in LDS, two
// barriers/kt) with the SPILL killed:
//   - plain __launch_bounds__(256)  (R14's (256,3) drove VGPR to 84 + ~640MB
//     scratch traffic; R13's plain bounds gave 116 VGPR, no spill)
//   - V-stage loads issued AFTER softmax (sacc dead) -> 16 stage regs live
//     only across PV; K-stage issue stays at loop top (R13-proven).
// ---------------------------------------------------------------------------
__global__ __launch_bounds__(256) void attn_kernel(
    const bf16_t* __restrict__ q_ws, const bf16_t* __restrict__ k_ws,
    const bf16_t* __restrict__ vt_ws, float* __restrict__ out)
{
    __shared__ __align__(16) bf16_t klds[64 * 136];      // 17408 B
    __shared__ __align__(16) bf16_t vlds[8192];          // 16384 B (one kt V tile)
    __shared__ __align__(16) bf16_t plds[4][32 * 76];    // 19456 B

    const int tid  = threadIdx.x;
    const int lane = tid & 63;
    const int w    = tid >> 6;
    const int lrow = lane & 15;
    const int lgrp = lane >> 4;

    const int p     = blockIdx.x >> 2;
    const int qt    = blockIdx.x & 3;
    const int qbase = qt * 128 + w * 32;

    const bf16_t* kbase = k_ws  + (size_t)p * (512 * 128);
    const bf16_t* vbase = vt_ws + (size_t)p * 65536;     // fragment-tiled

    // ---- staging maps (block stages one 16KB K tile + one 16KB V tile) ----
    const bf16_t* gk[4];
    int loff[4];
#pragma unroll
    for (int t = 0; t < 4; ++t) {
        const int c   = t * 256 + tid;
        const int row = c >> 4;
        const int off = (c & 15) * 8;
        gk[t]   = kbase + (size_t)row * 128 + off;   // + kt*8192 per tile
        loff[t] = row * 136 + off;
    }
    // V tile is contiguous: chunk c covers elements c*8 .. c*8+7
    const int vcoff[4] = { tid * 8, (256 + tid) * 8, (512 + tid) * 8, (768 + tid) * 8 };

    // ---- Q fragments (2 subtiles x 4 k-slices), resident all kernel ----
    bf16x8 qfr[2][4];
#pragma unroll
    for (int q2 = 0; q2 < 2; ++q2) {
        const bf16_t* qp = q_ws + ((size_t)p * 512 + qbase + q2 * 16 + lrow) * 128 + lgrp * 8;
#pragma unroll
        for (int ks = 0; ks < 4; ++ks)
            qfr[q2][ks] = *reinterpret_cast<const bf16x8*>(qp + ks * 32);
    }

    f32x4 oacc[2][8];
#pragma unroll
    for (int q2 = 0; q2 < 2; ++q2)
#pragma unroll
        for (int i = 0; i < 8; ++i) oacc[q2][i] = zero4();
    float psum[2][4];               // lane-local partial row-sums
#pragma unroll
    for (int q2 = 0; q2 < 2; ++q2)
#pragma unroll
        for (int r = 0; r < 4; ++r) psum[q2][r] = 0.f;

    // scale * log2(e): softmax in exp2 domain (v_exp_f32 is native exp2)
    const float c2 = 0.08838834764831845f * 1.4426950408889634f;
    bf16_t* pw = plds[w];

    // ---- prologue: stage kt=0 (K and V) ----
    {
        uint4 k0[4], v0[4];
#pragma unroll
        for (int t = 0; t < 4; ++t) {
            k0[t] = *reinterpret_cast<const uint4*>(gk[t]);
            v0[t] = *reinterpret_cast<const uint4*>(vbase + vcoff[t]);
        }
#pragma unroll
        for (int t = 0; t < 4; ++t) {
            *reinterpret_cast<uint4*>(&klds[loff[t]]) = k0[t];
            *reinterpret_cast<uint4*>(&vlds[vcoff[t]]) = v0[t];
        }
    }
    __syncthreads();

    for (int kt = 0; kt < 8; ++kt) {
        // K-stage loads for kt+1: issue at top (R13-proven live range)
        uint4 kstg[4];
        if (kt < 7) {
#pragma unroll
            for (int t = 0; t < 4; ++t)
                kstg[t] = *reinterpret_cast<const uint4*>(gk[t] + (size_t)(kt + 1) * 8192);
        }

        // ---- S = Q K^T : 32 queries x 64 keys (K from LDS) ----
        f32x4 sacc[2][4];
#pragma unroll
        for (int q2 = 0; q2 < 2; ++q2)
#pragma unroll
            for (int nt = 0; nt < 4; ++nt) sacc[q2][nt] = zero4();
#pragma unroll
        for (int nt = 0; nt < 4; ++nt) {
            const bf16_t* kp = &klds[(nt * 16 + lrow) * 136 + lgrp * 8];
#pragma unroll
            for (int ks = 0; ks < 4; ++ks) {
                const bf16x8 kf = *reinterpret_cast<const bf16x8*>(kp + ks * 32);
                sacc[0][nt] = MFMA16(qfr[0][ks], kf, sacc[0][nt]);
                sacc[1][nt] = MFMA16(qfr[1][ks], kf, sacc[1][nt]);
            }
        }

        // ---- static-max softmax: P = exp2(S*c2 - 12) ----
#pragma unroll
        for (int q2 = 0; q2 < 2; ++q2) {
#pragma unroll
            for (int r = 0; r < 4; ++r) {
                float rsum = psum[q2][r];
#pragma unroll
                for (int nt = 0; nt < 4; ++nt) {
                    const float e = exp2f(sacc[q2][nt][r] * c2 - 12.0f);
                    pw[(q2 * 16 + lgrp * 4 + r) * 76 + nt * 16 + lrow] = (bf16_t)e;
                    rsum += e;
                }
                psum[q2][r] = rsum;
            }
        }

        // V-stage loads for kt+1: issue here (sacc dead) -> live across PV only
        uint4 vstg[4];
        if (kt < 7) {
#pragma unroll
            for (int t = 0; t < 4; ++t)
                vstg[t] = *reinterpret_cast<const uint4*>(vbase + (size_t)(kt + 1) * 8192 + vcoff[t]);
        }

        // ---- O += P V  (V from LDS: 16 independent ds_read_b128) ----
#pragma unroll
        for (int ks2 = 0; ks2 < 2; ++ks2) {
            const bf16x8 pf0 = *reinterpret_cast<const bf16x8*>(
                pw + lrow * 76 + ks2 * 32 + lgrp * 8);
            const bf16x8 pf1 = *reinterpret_cast<const bf16x8*>(
                pw + (16 + lrow) * 76 + ks2 * 32 + lgrp * 8);
            const bf16_t* vp = &vlds[ks2 * 4096 + lane * 8];
#pragma unroll
            for (int f8 = 0; f8 < 8; ++f8) {
                const bf16x8 vf = *reinterpret_cast<const bf16x8*>(vp + f8 * 512);
                oacc[0][f8] = MFMA16(pf0, vf, oacc[0][f8]);
                oacc[1][f8] = MFMA16(pf1, vf, oacc[1][f8]);
            }
        }

        // ---- barrier; write prefetched K+V; barrier ----
        if (kt < 7) {
            __syncthreads();               // all reads of klds/vlds done
#pragma unroll
            for (int t = 0; t < 4; ++t) {
                *reinterpret_cast<uint4*>(&klds[loff[t]]) = kstg[t];
                *reinterpret_cast<uint4*>(&vlds[vcoff[t]]) = vstg[t];
            }
            __syncthreads();               // writes visible before next QK/PV
        }
    }

    // ---- epilogue: single shfl-tree row-sum reduce, then O / ssum ----
#pragma unroll
    for (int q2 = 0; q2 < 2; ++q2) {
        float* op = out + ((size_t)p * 512 + qbase + q2 * 16) * 128;
#pragma unroll
        for (int r = 0; r < 4; ++r) {
            float s = psum[q2][r];
            s += __shfl_xor(s, 1);
            s += __shfl_xor(s, 2);
            s += __shfl_xor(s, 4);
            s += __shfl_xor(s, 8);
            const float inv = 1.0f / s;
#pragma unroll
            for (int f8 = 0; f8 < 8; ++f8)
                op[(lgrp * 4 + r) * 128 + f8 * 16 + lrow] = oacc[q2][f8][r] * inv;
        }
    }
}

// ---------------------------------------------------------------------------
extern "C" void kernel_launch(void* const* d_in, const int* in_sizes, int n_in,
                              void* d_out, int out_size, void* d_ws, size_t ws_size,
                              hipStream_t stream) {
    const float* x      = (const float*)d_in[0];
    const float* nscale = (const float*)d_in[1];
    const float* wq     = (const float*)d_in[2];
    const float* wk     = (const float*)d_in[3];
    const float* wv     = (const float*)d_in[4];
    const float* bv     = (const float*)d_in[5];
    float* out = (float*)d_out;

    // workspace: q (64 MiB) | k (64 MiB) | vT fragment-tiled (64 MiB), bf16
    char* ws = (char*)d_ws;
    bf16_t* q_ws  = (bf16_t*)ws;
    bf16_t* k_ws  = (bf16_t*)(ws + ((size_t)64 << 20));
    bf16_t* vt_ws = (bf16_t*)(ws + ((size_t)128 << 20));

    qkv_kernel<<<dim3(4096), dim3(256), 0, stream>>>(
        x, nscale, wq, wk, wv, bv, q_ws, k_ws, vt_ws);
    attn_kernel<<<dim3(2048), dim3(256), 0, stream>>>(
        q_ws, k_ws, vt_ws, out);
}

// Round 16
// 437.012 us; speedup vs baseline: 1.2010x; 1.2010x over previous
//
#include <hip/hip_runtime.h>
#include <stdint.h>

using bf16_t = __bf16;
using bf16x8 = __attribute__((ext_vector_type(8))) bf16_t;
using bf16x4 = __attribute__((ext_vector_type(4))) bf16_t;
using f32x4  = __attribute__((ext_vector_type(4))) float;

#define MFMA16(a,b,c) __builtin_amdgcn_mfma_f32_16x16x32_bf16((a),(b),(c),0,0,0)

__device__ inline f32x4 zero4() { f32x4 z; z[0]=0.f; z[1]=0.f; z[2]=0.f; z[3]=0.f; return z; }

// ---------------------------------------------------------------------------
// Kernel 0: one-shot f32->bf16 weight conversion (wq|wk|wv -> 96KB in ws).
// ---------------------------------------------------------------------------
__global__ __launch_bounds__(256) void wconv_kernel(
    const float* __restrict__ wq, const float* __restrict__ wk,
    const float* __restrict__ wv, bf16_t* __restrict__ dst)
{
    const int i = blockIdx.x * 256 + threadIdx.x;   // 4096 threads, 1 float4 each
    const float* srcs[3] = { wq, wk, wv };
#pragma unroll
    for (int m = 0; m < 3; ++m) {
        const float4 v = reinterpret_cast<const float4*>(srcs[m])[i];
        bf16x4 o;
        o[0] = (bf16_t)v.x; o[1] = (bf16_t)v.y; o[2] = (bf16_t)v.z; o[3] = (bf16_t)v.w;
        *reinterpret_cast<bf16x4*>(dst + m * 16384 + i * 4) = o;
    }
}

// ---------------------------------------------------------------------------
// Kernel 1: RMSNorm + QKV projection. R13-green structure; template param
// selects bf16 pre-converted weights (1 load, no cvt) vs original f32 path.
// vt_ws stored PV-fragment-tiled: 16B unit = ((kt*2+ks2)*8+f8)*64 + lane.
// ---------------------------------------------------------------------------
template<int BF16W>
__global__ __launch_bounds__(256) void qkv_kernel(
    const float* __restrict__ x, const float* __restrict__ nscale,
    const float* __restrict__ wq, const float* __restrict__ wk,
    const float* __restrict__ wv, const float* __restrict__ bv,
    const bf16_t* __restrict__ wb,            // bf16 weights (wq|wk|wv), if BF16W
    bf16_t* __restrict__ q_ws, bf16_t* __restrict__ k_ws,
    bf16_t* __restrict__ vt_ws)
{
    __shared__ __align__(16) union SM {
        bf16_t h[64 * 136];                                     // 17408 B
        struct { bf16_t qk[64 * 264]; bf16_t vt[128 * 72]; } o; // 33792+18432 B
    } sm;

    const int tid   = threadIdx.x;
    const int mbase = blockIdx.x * 64;

    // ---- Phase 1: RMSNorm -> sm.h (bf16, row stride 136) ----
    {
        const int row = tid >> 2;
        const int qtr = tid & 3;
        const float4* xr = reinterpret_cast<const float4*>(x + (size_t)(mbase + row) * 128) + qtr * 8;
        const float4* sc = reinterpret_cast<const float4*>(nscale) + qtr * 8;
        float4 xv[8];
        float ss = 0.f;
#pragma unroll
        for (int i = 0; i < 8; ++i) {
            xv[i] = xr[i];
            ss += xv[i].x*xv[i].x + xv[i].y*xv[i].y + xv[i].z*xv[i].z + xv[i].w*xv[i].w;
        }
        ss += __shfl_xor(ss, 1);
        ss += __shfl_xor(ss, 2);
        const float rs = rsqrtf(ss * (1.0f / 128.0f) + 1e-6f);
#pragma unroll
        for (int i = 0; i < 8; ++i) {
            const float4 s = sc[i];
            bf16x4 hv;
            hv[0] = (bf16_t)(xv[i].x * rs * s.x);
            hv[1] = (bf16_t)(xv[i].y * rs * s.y);
            hv[2] = (bf16_t)(xv[i].z * rs * s.z);
            hv[3] = (bf16_t)(xv[i].w * rs * s.w);
            *reinterpret_cast<bf16x4*>(&sm.h[row * 136 + qtr * 32 + i * 4]) = hv;
        }
    }
    __syncthreads();

    const int lane = tid & 63;
    const int w    = tid >> 6;
    const int lrow = lane & 15;
    const int lgrp = lane >> 4;

    // ---- A fragments: full 64x128 h tile ----
    bf16x8 afr[4][4];
#pragma unroll
    for (int mt = 0; mt < 4; ++mt)
#pragma unroll
        for (int ks = 0; ks < 4; ++ks)
            afr[mt][ks] = *reinterpret_cast<const bf16x8*>(
                &sm.h[(mt * 16 + lrow) * 136 + ks * 32 + lgrp * 8]);
    __syncthreads();   // h dead; LDS reused as sm.o

    // ---- GEMM per nt tile; results -> LDS ----
#pragma unroll
    for (int nt = 0; nt < 6; ++nt) {
        const int gcol = w * 96 + nt * 16;                 // wave-uniform, 0..383
        const bool is_v = (gcol >= 256);

        f32x4 acc[4];
#pragma unroll
        for (int mt = 0; mt < 4; ++mt) acc[mt] = zero4();

#pragma unroll
        for (int ks = 0; ks < 4; ++ks) {
            bf16x8 bfr;
            if (BF16W) {
                bfr = *reinterpret_cast<const bf16x8*>(
                    wb + (size_t)(gcol < 128 ? 0 : (gcol < 256 ? 16384 : 32768))
                       + (size_t)((gcol & 127) + lrow) * 128 + ks * 32 + lgrp * 8);
            } else {
                const float* wptr = (gcol < 128) ? wq : ((gcol < 256) ? wk : wv);
                const float* wrow = wptr + (size_t)((gcol & 127) + lrow) * 128 + lgrp * 8;
                const float4 w0 = *reinterpret_cast<const float4*>(wrow + ks * 32);
                const float4 w1 = *reinterpret_cast<const float4*>(wrow + ks * 32 + 4);
                bfr[0] = (bf16_t)w0.x; bfr[1] = (bf16_t)w0.y;
                bfr[2] = (bf16_t)w0.z; bfr[3] = (bf16_t)w0.w;
                bfr[4] = (bf16_t)w1.x; bfr[5] = (bf16_t)w1.y;
                bfr[6] = (bf16_t)w1.z; bfr[7] = (bf16_t)w1.w;
            }
            if (!is_v) {
#pragma unroll
                for (int mt = 0; mt < 4; ++mt)
                    acc[mt] = MFMA16(bfr, afr[mt][ks], acc[mt]);   // C[feat][pos]
            } else {
#pragma unroll
                for (int mt = 0; mt < 4; ++mt)
                    acc[mt] = MFMA16(afr[mt][ks], bfr, acc[mt]);   // C[pos][feat]
            }
        }

        if (!is_v) {
            // per-lane: pos = mt*16+lrow, feats gcol+lgrp*4 .. +3
#pragma unroll
            for (int mt = 0; mt < 4; ++mt) {
                bf16x4 o4;
                o4[0] = (bf16_t)acc[mt][0]; o4[1] = (bf16_t)acc[mt][1];
                o4[2] = (bf16_t)acc[mt][2]; o4[3] = (bf16_t)acc[mt][3];
                *reinterpret_cast<bf16x4*>(&sm.o.qk[(mt*16 + lrow) * 264 + gcol + lgrp*4]) = o4;
            }
        } else {
            // per-lane: feat = (gcol-256)+lrow, pos = mt*16+lgrp*4 .. +3
            const int f = (gcol - 256) + lrow;
            const float bvf = bv[f];
#pragma unroll
            for (int mt = 0; mt < 4; ++mt) {
                bf16x4 o4;
                o4[0] = (bf16_t)(acc[mt][0] + bvf); o4[1] = (bf16_t)(acc[mt][1] + bvf);
                o4[2] = (bf16_t)(acc[mt][2] + bvf); o4[3] = (bf16_t)(acc[mt][3] + bvf);
                *reinterpret_cast<bf16x4*>(&sm.o.vt[f * 72 + mt*16 + lgrp*4]) = o4;
            }
        }
    }
    __syncthreads();

    // ---- coalesced store-out ----
    const int p  = mbase >> 9;
    const int kb = mbase & 511;
#pragma unroll
    for (int it = 0; it < 8; ++it) {
        const int c   = it * 256 + tid;     // 2048 chunks of 8 bf16
        const int pos = c >> 5;
        const int col = (c & 31) * 8;
        const bf16x8 vv = *reinterpret_cast<const bf16x8*>(&sm.o.qk[pos * 264 + col]);
        bf16_t* dst = (col < 128) ? (q_ws + (size_t)(mbase + pos) * 128 + col)
                                  : (k_ws + (size_t)(mbase + pos) * 128 + (col - 128));
        *reinterpret_cast<bf16x8*>(dst) = vv;
    }
    // V: LDS vt[f][ko..ko+7] -> fragment-tiled global layout.
    {
        const int kt = kb >> 6;
#pragma unroll
        for (int it = 0; it < 4; ++it) {
            const int c  = it * 256 + tid;  // 1024 chunks of 8 bf16
            const int f  = c >> 3;
            const int ko = (c & 7) * 8;
            const int unit = ((kt * 2 + (ko >> 5)) * 8 + (f >> 4)) * 64
                             + ((ko >> 3) & 3) * 16 + (f & 15);
            *reinterpret_cast<bf16x8*>(vt_ws + (size_t)p * 65536 + (size_t)unit * 8) =
                *reinterpret_cast<const bf16x8*>(&sm.o.vt[f * 72 + ko]);
        }
    }
}

// ---------------------------------------------------------------------------
// Kernel 2: flash attention. R13 per-wave code, 8-WAVE blocks (512 thr,
// 256 queries): K tile staged once per 256 q (was 128), LDS = 17408(K) +
// 38912(P) = 56320 B -> 2 blocks/CU = 16 waves/CU (was 12). Single K buffer,
// 2 cheap barriers/kt; kstg shrinks to 2 regs of uint4 (less VGPR than R13).
// ---------------------------------------------------------------------------
__global__ __launch_bounds__(512, 2) void attn_kernel(
    const bf16_t* __restrict__ q_ws, const bf16_t* __restrict__ k_ws,
    const bf16_t* __restrict__ vt_ws, float* __restrict__ out)
{
    __shared__ __align__(16) bf16_t klds[64 * 136];      // 17408 B
    __shared__ __align__(16) bf16_t plds[8][32 * 76];    // 38912 B

    const int tid  = threadIdx.x;
    const int lane = tid & 63;
    const int w    = tid >> 6;          // 0..7
    const int lrow = lane & 15;
    const int lgrp = lane >> 4;

    const int p     = blockIdx.x >> 1;
    const int qt    = blockIdx.x & 1;
    const int qbase = qt * 256 + w * 32;

    const bf16_t* kbase = k_ws  + (size_t)p * (512 * 128);
    const bf16_t* vbase = vt_ws + (size_t)p * 65536;     // fragment-tiled

    // ---- staging map (512 threads stage one 64x128 K tile = 16 KiB) ----
    const bf16_t* gk[2];
    int loff[2];
#pragma unroll
    for (int t = 0; t < 2; ++t) {
        const int c   = t * 512 + tid;       // 1024 chunks of 16B
        const int row = c >> 4;
        const int off = (c & 15) * 8;
        gk[t]   = kbase + (size_t)row * 128 + off;   // + kt*8192 per tile
        loff[t] = row * 136 + off;
    }

    // ---- Q fragments (2 subtiles x 4 k-slices), resident all kernel ----
    bf16x8 qfr[2][4];
#pragma unroll
    for (int q2 = 0; q2 < 2; ++q2) {
        const bf16_t* qp = q_ws + ((size_t)p * 512 + qbase + q2 * 16 + lrow) * 128 + lgrp * 8;
#pragma unroll
        for (int ks = 0; ks < 4; ++ks)
            qfr[q2][ks] = *reinterpret_cast<const bf16x8*>(qp + ks * 32);
    }

    f32x4 oacc[2][8];
#pragma unroll
    for (int q2 = 0; q2 < 2; ++q2)
#pragma unroll
        for (int i = 0; i < 8; ++i) oacc[q2][i] = zero4();
    float psum[2][4];               // lane-local partial row-sums
#pragma unroll
    for (int q2 = 0; q2 < 2; ++q2)
#pragma unroll
        for (int r = 0; r < 4; ++r) psum[q2][r] = 0.f;

    // scale * log2(e): softmax in exp2 domain (v_exp_f32 is native exp2)
    const float c2 = 0.08838834764831845f * 1.4426950408889634f;
    bf16_t* pw = plds[w];

    // ---- prologue: stage kt=0 ----
    {
        uint4 s0[2];
#pragma unroll
        for (int t = 0; t < 2; ++t)
            s0[t] = *reinterpret_cast<const uint4*>(gk[t]);
#pragma unroll
        for (int t = 0; t < 2; ++t)
            *reinterpret_cast<uint4*>(&klds[loff[t]]) = s0[t];
    }
    __syncthreads();

    for (int kt = 0; kt < 8; ++kt) {
        // K-stage loads for kt+1: issue at top, consumed after barrier1
        uint4 kstg[2];
        if (kt < 7) {
#pragma unroll
            for (int t = 0; t < 2; ++t)
                kstg[t] = *reinterpret_cast<const uint4*>(gk[t] + (size_t)(kt + 1) * 8192);
        }

        // ---- S = Q K^T : 32 queries x 64 keys (K from LDS) ----
        f32x4 sacc[2][4];
#pragma unroll
        for (int q2 = 0; q2 < 2; ++q2)
#pragma unroll
            for (int nt = 0; nt < 4; ++nt) sacc[q2][nt] = zero4();
#pragma unroll
        for (int nt = 0; nt < 4; ++nt) {
            const bf16_t* kp = &klds[(nt * 16 + lrow) * 136 + lgrp * 8];
#pragma unroll
            for (int ks = 0; ks < 4; ++ks) {
                const bf16x8 kf = *reinterpret_cast<const bf16x8*>(kp + ks * 32);
                sacc[0][nt] = MFMA16(qfr[0][ks], kf, sacc[0][nt]);
                sacc[1][nt] = MFMA16(qfr[1][ks], kf, sacc[1][nt]);
            }
        }
        if (kt < 7) __syncthreads();   // barrier 1: all K reads of tile kt done

        // ---- static-max softmax: P = exp2(S*c2 - 12) ----
#pragma unroll
        for (int q2 = 0; q2 < 2; ++q2) {
#pragma unroll
            for (int r = 0; r < 4; ++r) {
                float rsum = psum[q2][r];
#pragma unroll
                for (int nt = 0; nt < 4; ++nt) {
                    const float e = exp2f(sacc[q2][nt][r] * c2 - 12.0f);
                    pw[(q2 * 16 + lgrp * 4 + r) * 76 + nt * 16 + lrow] = (bf16_t)e;
                    rsum += e;
                }
                psum[q2][r] = rsum;
            }
        }

        // write prefetched K tile (safe: all waves past barrier 1)
        if (kt < 7) {
#pragma unroll
            for (int t = 0; t < 2; ++t)
                *reinterpret_cast<uint4*>(&klds[loff[t]]) = kstg[t];
        }

        // ---- O += P V  (V direct from global, fragment-tiled contiguous) ----
#pragma unroll
        for (int ks2 = 0; ks2 < 2; ++ks2) {
            const bf16x8 pf0 = *reinterpret_cast<const bf16x8*>(
                pw + lrow * 76 + ks2 * 32 + lgrp * 8);
            const bf16x8 pf1 = *reinterpret_cast<const bf16x8*>(
                pw + (16 + lrow) * 76 + ks2 * 32 + lgrp * 8);
            const bf16_t* vp = vbase + (size_t)(kt * 2 + ks2) * 4096 + lane * 8;
#pragma unroll
            for (int f8 = 0; f8 < 8; ++f8) {
                const bf16x8 vf = *reinterpret_cast<const bf16x8*>(vp + f8 * 512);
                oacc[0][f8] = MFMA16(pf0, vf, oacc[0][f8]);
                oacc[1][f8] = MFMA16(pf1, vf, oacc[1][f8]);
            }
        }

        if (kt < 7) __syncthreads();   // barrier 2: K writes visible for next QK
    }

    // ---- epilogue: single shfl-tree row-sum reduce, then O / ssum ----
#pragma unroll
    for (int q2 = 0; q2 < 2; ++q2) {
        float* op = out + ((size_t)p * 512 + qbase + q2 * 16) * 128;
#pragma unroll
        for (int r = 0; r < 4; ++r) {
            float s = psum[q2][r];
            s += __shfl_xor(s, 1);
            s += __shfl_xor(s, 2);
            s += __shfl_xor(s, 4);
            s += __shfl_xor(s, 8);
            const float inv = 1.0f / s;
#pragma unroll
            for (int f8 = 0; f8 < 8; ++f8)
                op[(lgrp * 4 + r) * 128 + f8 * 16 + lrow] = oacc[q2][f8][r] * inv;
        }
    }
}

// ---------------------------------------------------------------------------
extern "C" void kernel_launch(void* const* d_in, const int* in_sizes, int n_in,
                              void* d_out, int out_size, void* d_ws, size_t ws_size,
                              hipStream_t stream) {
    const float* x      = (const float*)d_in[0];
    const float* nscale = (const float*)d_in[1];
    const float* wq     = (const float*)d_in[2];
    const float* wk     = (const float*)d_in[3];
    const float* wv     = (const float*)d_in[4];
    const float* bv     = (const float*)d_in[5];
    float* out = (float*)d_out;

    // workspace: q (64 MiB) | k (64 MiB) | vT fragment-tiled (64 MiB) | bf16 W (96 KiB)
    char* ws = (char*)d_ws;
    bf16_t* q_ws  = (bf16_t*)ws;
    bf16_t* k_ws  = (bf16_t*)(ws + ((size_t)64 << 20));
    bf16_t* vt_ws = (bf16_t*)(ws + ((size_t)128 << 20));
    const size_t base = (size_t)192 << 20;
    const bool bf16w = (ws_size >= base + 3 * 16384 * sizeof(bf16_t));
    bf16_t* wb = (bf16_t*)(ws + base);

    if (bf16w) {
        wconv_kernel<<<dim3(16), dim3(256), 0, stream>>>(wq, wk, wv, wb);
        qkv_kernel<1><<<dim3(4096), dim3(256), 0, stream>>>(
            x, nscale, wq, wk, wv, bv, wb, q_ws, k_ws, vt_ws);
    } else {
        qkv_kernel<0><<<dim3(4096), dim3(256), 0, stream>>>(
            x, nscale, wq, wk, wv, bv, (const bf16_t*)nullptr, q_ws, k_ws, vt_ws);
    }
    attn_kernel<<<dim3(1024), dim3(512), 0, stream>>>(
        q_ws, k_ws, vt_ws, out);
}

// Round 17
// 303.307 us; speedup vs baseline: 1.7304x; 1.4408x over previous
//
#include <hip/hip_runtime.h>
#include <stdint.h>

using bf16_t = __bf16;
using bf16x8 = __attribute__((ext_vector_type(8))) bf16_t;
using bf16x4 = __attribute__((ext_vector_type(4))) bf16_t;
using f32x4  = __attribute__((ext_vector_type(4))) float;
using u32    = uint32_t;

#define MFMA16(a,b,c) __builtin_amdgcn_mfma_f32_16x16x32_bf16((a),(b),(c),0,0,0)

__device__ inline f32x4 zero4() { f32x4 z; z[0]=0.f; z[1]=0.f; z[2]=0.f; z[3]=0.f; return z; }

__device__ inline u32 pkbf16(float a, float b) {
    union { bf16_t h[2]; u32 u; } t;
    t.h[0] = (bf16_t)a; t.h[1] = (bf16_t)b;   // low half = even (lower) key
    return t.u;
}

// ---------------------------------------------------------------------------
// Kernel 0: one-shot f32->bf16 weight conversion (wq|wk|wv -> 96KB in ws).
// ---------------------------------------------------------------------------
__global__ __launch_bounds__(256) void wconv_kernel(
    const float* __restrict__ wq, const float* __restrict__ wk,
    const float* __restrict__ wv, bf16_t* __restrict__ dst)
{
    const int i = blockIdx.x * 256 + threadIdx.x;
    const float* srcs[3] = { wq, wk, wv };
#pragma unroll
    for (int m = 0; m < 3; ++m) {
        const float4 v = reinterpret_cast<const float4*>(srcs[m])[i];
        bf16x4 o;
        o[0] = (bf16_t)v.x; o[1] = (bf16_t)v.y; o[2] = (bf16_t)v.z; o[3] = (bf16_t)v.w;
        *reinterpret_cast<bf16x4*>(dst + m * 16384 + i * 4) = o;
    }
}

// ---------------------------------------------------------------------------
// Kernel 1: RMSNorm + QKV projection. VERBATIM from round 16 (PASSED, ~103us).
// vt_ws stored PV-fragment-tiled: 16B unit = ((kt*2+ks2)*8+f8)*64 + lane.
// ---------------------------------------------------------------------------
template<int BF16W>
__global__ __launch_bounds__(256) void qkv_kernel(
    const float* __restrict__ x, const float* __restrict__ nscale,
    const float* __restrict__ wq, const float* __restrict__ wk,
    const float* __restrict__ wv, const float* __restrict__ bv,
    const bf16_t* __restrict__ wb,
    bf16_t* __restrict__ q_ws, bf16_t* __restrict__ k_ws,
    bf16_t* __restrict__ vt_ws)
{
    __shared__ __align__(16) union SM {
        bf16_t h[64 * 136];
        struct { bf16_t qk[64 * 264]; bf16_t vt[128 * 72]; } o;
    } sm;

    const int tid   = threadIdx.x;
    const int mbase = blockIdx.x * 64;

    {
        const int row = tid >> 2;
        const int qtr = tid & 3;
        const float4* xr = reinterpret_cast<const float4*>(x + (size_t)(mbase + row) * 128) + qtr * 8;
        const float4* sc = reinterpret_cast<const float4*>(nscale) + qtr * 8;
        float4 xv[8];
        float ss = 0.f;
#pragma unroll
        for (int i = 0; i < 8; ++i) {
            xv[i] = xr[i];
            ss += xv[i].x*xv[i].x + xv[i].y*xv[i].y + xv[i].z*xv[i].z + xv[i].w*xv[i].w;
        }
        ss += __shfl_xor(ss, 1);
        ss += __shfl_xor(ss, 2);
        const float rs = rsqrtf(ss * (1.0f / 128.0f) + 1e-6f);
#pragma unroll
        for (int i = 0; i < 8; ++i) {
            const float4 s = sc[i];
            bf16x4 hv;
            hv[0] = (bf16_t)(xv[i].x * rs * s.x);
            hv[1] = (bf16_t)(xv[i].y * rs * s.y);
            hv[2] = (bf16_t)(xv[i].z * rs * s.z);
            hv[3] = (bf16_t)(xv[i].w * rs * s.w);
            *reinterpret_cast<bf16x4*>(&sm.h[row * 136 + qtr * 32 + i * 4]) = hv;
        }
    }
    __syncthreads();

    const int lane = tid & 63;
    const int w    = tid >> 6;
    const int lrow = lane & 15;
    const int lgrp = lane >> 4;

    bf16x8 afr[4][4];
#pragma unroll
    for (int mt = 0; mt < 4; ++mt)
#pragma unroll
        for (int ks = 0; ks < 4; ++ks)
            afr[mt][ks] = *reinterpret_cast<const bf16x8*>(
                &sm.h[(mt * 16 + lrow) * 136 + ks * 32 + lgrp * 8]);
    __syncthreads();

#pragma unroll
    for (int nt = 0; nt < 6; ++nt) {
        const int gcol = w * 96 + nt * 16;
        const bool is_v = (gcol >= 256);

        f32x4 acc[4];
#pragma unroll
        for (int mt = 0; mt < 4; ++mt) acc[mt] = zero4();

#pragma unroll
        for (int ks = 0; ks < 4; ++ks) {
            bf16x8 bfr;
            if (BF16W) {
                bfr = *reinterpret_cast<const bf16x8*>(
                    wb + (size_t)(gcol < 128 ? 0 : (gcol < 256 ? 16384 : 32768))
                       + (size_t)((gcol & 127) + lrow) * 128 + ks * 32 + lgrp * 8);
            } else {
                const float* wptr = (gcol < 128) ? wq : ((gcol < 256) ? wk : wv);
                const float* wrow = wptr + (size_t)((gcol & 127) + lrow) * 128 + lgrp * 8;
                const float4 w0 = *reinterpret_cast<const float4*>(wrow + ks * 32);
                const float4 w1 = *reinterpret_cast<const float4*>(wrow + ks * 32 + 4);
                bfr[0] = (bf16_t)w0.x; bfr[1] = (bf16_t)w0.y;
                bfr[2] = (bf16_t)w0.z; bfr[3] = (bf16_t)w0.w;
                bfr[4] = (bf16_t)w1.x; bfr[5] = (bf16_t)w1.y;
                bfr[6] = (bf16_t)w1.z; bfr[7] = (bf16_t)w1.w;
            }
            if (!is_v) {
#pragma unroll
                for (int mt = 0; mt < 4; ++mt)
                    acc[mt] = MFMA16(bfr, afr[mt][ks], acc[mt]);
            } else {
#pragma unroll
                for (int mt = 0; mt < 4; ++mt)
                    acc[mt] = MFMA16(afr[mt][ks], bfr, acc[mt]);
            }
        }

        if (!is_v) {
#pragma unroll
            for (int mt = 0; mt < 4; ++mt) {
                bf16x4 o4;
                o4[0] = (bf16_t)acc[mt][0]; o4[1] = (bf16_t)acc[mt][1];
                o4[2] = (bf16_t)acc[mt][2]; o4[3] = (bf16_t)acc[mt][3];
                *reinterpret_cast<bf16x4*>(&sm.o.qk[(mt*16 + lrow) * 264 + gcol + lgrp*4]) = o4;
            }
        } else {
            const int f = (gcol - 256) + lrow;
            const float bvf = bv[f];
#pragma unroll
            for (int mt = 0; mt < 4; ++mt) {
                bf16x4 o4;
                o4[0] = (bf16_t)(acc[mt][0] + bvf); o4[1] = (bf16_t)(acc[mt][1] + bvf);
                o4[2] = (bf16_t)(acc[mt][2] + bvf); o4[3] = (bf16_t)(acc[mt][3] + bvf);
                *reinterpret_cast<bf16x4*>(&sm.o.vt[f * 72 + mt*16 + lgrp*4]) = o4;
            }
        }
    }
    __syncthreads();

    const int p  = mbase >> 9;
    const int kb = mbase & 511;
#pragma unroll
    for (int it = 0; it < 8; ++it) {
        const int c   = it * 256 + tid;
        const int pos = c >> 5;
        const int col = (c & 31) * 8;
        const bf16x8 vv = *reinterpret_cast<const bf16x8*>(&sm.o.qk[pos * 264 + col]);
        bf16_t* dst = (col < 128) ? (q_ws + (size_t)(mbase + pos) * 128 + col)
                                  : (k_ws + (size_t)(mbase + pos) * 128 + (col - 128));
        *reinterpret_cast<bf16x8*>(dst) = vv;
    }
    {
        const int kt = kb >> 6;
#pragma unroll
        for (int it = 0; it < 4; ++it) {
            const int c  = it * 256 + tid;
            const int f  = c >> 3;
            const int ko = (c & 7) * 8;
            const int unit = ((kt * 2 + (ko >> 5)) * 8 + (f >> 4)) * 64
                             + ((ko >> 3) & 3) * 16 + (f & 15);
            *reinterpret_cast<bf16x8*>(vt_ws + (size_t)p * 65536 + (size_t)unit * 8) =
                *reinterpret_cast<const bf16x8*>(&sm.o.vt[f * 72 + ko]);
        }
    }
}

// ---------------------------------------------------------------------------
// Kernel 2: flash attention, SWAPPED-OPERAND structure (m214-style):
//  - QK^T as mfma(K, Q): lane holds S[key = nt*16+lgrp*4+r][query = lane&15]
//    -> softmax (static-max) 100% lane-local, P packed to bf16 IN REGISTERS.
//  - P -> PV B-fragment via 16 __shfl per kt (no LDS round trip, no plds).
//  - PV as mfma(V^T, P): same vf fragment; O^T[feat][query] -> float4 stores.
//  - 16 q/wave, 8 waves/block (128 q); K AND V double-buffered in LDS
//    (67584 B -> 2 blocks/CU = 16 waves/CU), reg-staged, ONE barrier/kt.
// ---------------------------------------------------------------------------
__global__ __launch_bounds__(512, 2) void attn_kernel(
    const bf16_t* __restrict__ q_ws, const bf16_t* __restrict__ k_ws,
    const bf16_t* __restrict__ vt_ws, float* __restrict__ out)
{
    __shared__ __align__(16) bf16_t klds[2][64 * 136];   // 34816 B
    __shared__ __align__(16) bf16_t vlds[2][8192];       // 32768 B (fragment-tiled)

    const int tid  = threadIdx.x;
    const int lane = tid & 63;
    const int w    = tid >> 6;          // 0..7
    const int lrow = lane & 15;
    const int lgrp = lane >> 4;

    const int p    = blockIdx.x >> 2;
    const int qt   = blockIdx.x & 3;
    const int qrow = qt * 128 + w * 16 + lrow;     // this lane's query row

    const bf16_t* kbase = k_ws  + (size_t)p * (512 * 128);
    const bf16_t* vbase = vt_ws + (size_t)p * 65536;

    // ---- staging maps: 512 threads x 2 chunks of 16B per 16KB tile ----
    const bf16_t* gk[2];
    int loff[2];
#pragma unroll
    for (int t = 0; t < 2; ++t) {
        const int c   = t * 512 + tid;
        const int row = c >> 4;
        const int off = (c & 15) * 8;
        gk[t]   = kbase + (size_t)row * 128 + off;   // + kt*8192 per tile
        loff[t] = row * 136 + off;
    }
    const int vcoff[2] = { tid * 8, (512 + tid) * 8 };   // V tile contiguous

    // ---- Q fragments: 16 queries of this wave ----
    bf16x8 qfr[4];
    {
        const bf16_t* qp = q_ws + ((size_t)p * 512 + qrow) * 128 + lgrp * 8;
#pragma unroll
        for (int ks = 0; ks < 4; ++ks)
            qfr[ks] = *reinterpret_cast<const bf16x8*>(qp + ks * 32);
    }

    f32x4 oacc[8];
#pragma unroll
    for (int i = 0; i < 8; ++i) oacc[i] = zero4();
    float psum = 0.f;                   // lane-local over this lane's keys

    // shfl source lanes for P redistribution (derived: src lgrp' = (lgrp&1)*2 + (jj>>1))
    const int srcA = lrow + 32 * (lgrp & 1);   // jj = 0,1
    const int srcB = srcA + 16;                // jj = 2,3
    const bool hi  = (lgrp >= 2);              // dest nt-select bit

    const float c2 = 0.08838834764831845f * 1.4426950408889634f;

    // ---- prologue: stage kt=0 (K + V) into buf 0 ----
    {
        uint4 k0[2], v0[2];
#pragma unroll
        for (int t = 0; t < 2; ++t) {
            k0[t] = *reinterpret_cast<const uint4*>(gk[t]);
            v0[t] = *reinterpret_cast<const uint4*>(vbase + vcoff[t]);
        }
#pragma unroll
        for (int t = 0; t < 2; ++t) {
            *reinterpret_cast<uint4*>(&klds[0][loff[t]]) = k0[t];
            *reinterpret_cast<uint4*>(&vlds[0][vcoff[t]]) = v0[t];
        }
    }
    __syncthreads();

    for (int kt = 0; kt < 8; ++kt) {
        const int buf = kt & 1;
        // K-stage loads for kt+1 (latency hides under QK+softmax+PV)
        uint4 kstg[2];
        if (kt < 7) {
#pragma unroll
            for (int t = 0; t < 2; ++t)
                kstg[t] = *reinterpret_cast<const uint4*>(gk[t] + (size_t)(kt + 1) * 8192);
        }

        // ---- S^T = K Q : lane gets S[key = nt*16+lgrp*4+r][query = lrow] ----
        f32x4 sacc[4];
        sacc[0] = zero4(); sacc[1] = zero4(); sacc[2] = zero4(); sacc[3] = zero4();
#pragma unroll
        for (int nt = 0; nt < 4; ++nt) {
            const bf16_t* kp = &klds[buf][(nt * 16 + lrow) * 136 + lgrp * 8];
#pragma unroll
            for (int ks = 0; ks < 4; ++ks) {
                const bf16x8 kf = *reinterpret_cast<const bf16x8*>(kp + ks * 32);
                sacc[nt] = MFMA16(kf, qfr[ks], sacc[nt]);      // SWAPPED
            }
        }

        // ---- static-max softmax, fully lane-local; pack P to bf16 pairs ----
        u32 pk[4][2];
#pragma unroll
        for (int nt = 0; nt < 4; ++nt) {
            const float e0 = exp2f(sacc[nt][0] * c2 - 12.0f);
            const float e1 = exp2f(sacc[nt][1] * c2 - 12.0f);
            const float e2 = exp2f(sacc[nt][2] * c2 - 12.0f);
            const float e3 = exp2f(sacc[nt][3] * c2 - 12.0f);
            psum += (e0 + e1) + (e2 + e3);
            pk[nt][0] = pkbf16(e0, e1);
            pk[nt][1] = pkbf16(e2, e3);
        }

        // V-stage loads for kt+1 (sacc dead; live only across PV)
        uint4 vstg[2];
        if (kt < 7) {
#pragma unroll
            for (int t = 0; t < 2; ++t)
                vstg[t] = *reinterpret_cast<const uint4*>(vbase + (size_t)(kt + 1) * 8192 + vcoff[t]);
        }

        // ---- O^T += V^T P : P B-fragment assembled via shfl ----
#pragma unroll
        for (int ks2 = 0; ks2 < 2; ++ks2) {
            u32 wd[4];
#pragma unroll
            for (int jj = 0; jj < 4; ++jj) {
                const int src = (jj < 2) ? srcA : srcB;
                const u32 a = (u32)__shfl((int)pk[2 * ks2 + 0][jj & 1], src);
                const u32 b = (u32)__shfl((int)pk[2 * ks2 + 1][jj & 1], src);
                wd[jj] = hi ? b : a;
            }
            union { u32 u[4]; bf16x8 v; } pfB;
            pfB.u[0] = wd[0]; pfB.u[1] = wd[1]; pfB.u[2] = wd[2]; pfB.u[3] = wd[3];

            const bf16_t* vp = &vlds[buf][ks2 * 4096 + lane * 8];
#pragma unroll
            for (int f8 = 0; f8 < 8; ++f8) {
                const bf16x8 vf = *reinterpret_cast<const bf16x8*>(vp + f8 * 512);
                oacc[f8] = MFMA16(vf, pfB.v, oacc[f8]);        // A=V^T, B=P
            }
        }

        // ---- write prefetched K+V into the other buffer; one barrier ----
        if (kt < 7) {
#pragma unroll
            for (int t = 0; t < 2; ++t) {
                *reinterpret_cast<uint4*>(&klds[buf ^ 1][loff[t]]) = kstg[t];
                *reinterpret_cast<uint4*>(&vlds[buf ^ 1][vcoff[t]]) = vstg[t];
            }
        }
        __syncthreads();
    }

    // ---- epilogue: reduce psum across the 4 lgrp groups; write O ----
    float s = psum;
    s += __shfl_xor(s, 16);
    s += __shfl_xor(s, 32);
    const float inv = 1.0f / s;

    float* op = out + ((size_t)p * 512 + qrow) * 128;
#pragma unroll
    for (int f8 = 0; f8 < 8; ++f8) {
        float4 o;                        // feats f8*16 + lgrp*4 + (0..3)
        o.x = oacc[f8][0] * inv; o.y = oacc[f8][1] * inv;
        o.z = oacc[f8][2] * inv; o.w = oacc[f8][3] * inv;
        *reinterpret_cast<float4*>(op + f8 * 16 + lgrp * 4) = o;
    }
}

// ---------------------------------------------------------------------------
extern "C" void kernel_launch(void* const* d_in, const int* in_sizes, int n_in,
                              void* d_out, int out_size, void* d_ws, size_t ws_size,
                              hipStream_t stream) {
    const float* x      = (const float*)d_in[0];
    const float* nscale = (const float*)d_in[1];
    const float* wq     = (const float*)d_in[2];
    const float* wk     = (const float*)d_in[3];
    const float* wv     = (const float*)d_in[4];
    const float* bv     = (const float*)d_in[5];
    float* out = (float*)d_out;

    char* ws = (char*)d_ws;
    bf16_t* q_ws  = (bf16_t*)ws;
    bf16_t* k_ws  = (bf16_t*)(ws + ((size_t)64 << 20));
    bf16_t* vt_ws = (bf16_t*)(ws + ((size_t)128 << 20));
    const size_t base = (size_t)192 << 20;
    const bool bf16w = (ws_size >= base + 3 * 16384 * sizeof(bf16_t));
    bf16_t* wb = (bf16_t*)(ws + base);

    if (bf16w) {
        wconv_kernel<<<dim3(16), dim3(256), 0, stream>>>(wq, wk, wv, wb);
        qkv_kernel<1><<<dim3(4096), dim3(256), 0, stream>>>(
            x, nscale, wq, wk, wv, bv, wb, q_ws, k_ws, vt_ws);
    } else {
        qkv_kernel<0><<<dim3(4096), dim3(256), 0, stream>>>(
            x, nscale, wq, wk, wv, bv, (const bf16_t*)nullptr, q_ws, k_ws, vt_ws);
    }
    attn_kernel<<<dim3(2048), dim3(512), 0, stream>>>(
        q_ws, k_ws, vt_ws, out);
}